// Round 14
// baseline (84.423 us; speedup 1.0000x reference)
//
#include <hip/hip_runtime.h>

#define D 128
#define B 256
#define WMAX 64
#define SPILL_MAX 8192
#define NPART 8    // XCD count on MI355X; blockIdx % 8 ~ XCD (perf heuristic only)
#define NSLICE 4   // source slices; 12.8MB xb / 4 = 3.2MB fits a 4MB XCD L2

typedef float vfloat4 __attribute__((ext_vector_type(4)));
typedef float vfloat2 __attribute__((ext_vector_type(2)));

// ---------------------------------------------------------------------------
// GCN message passing, ELL + bf16 + XCD-partitioned build + source-sliced agg:
//   prep : cursor=0, out2=x (NT), xb=bf16(x)
//   place: 8 block-groups (one per XCD); group p scans ALL edges, keeps only
//          destinations in [n*p/8, n*(p+1)/8) -> XCD-local cursor/ssrc.
//   agg  : one node per 64-lane wave (4B/lane). Source list + weights staged
//          in LDS, counting-sorted into 4 source slices; gathers processed
//          slice-by-slice so the concurrent xb footprint per XCD ~ 3.2MB
//          (L2-resident) instead of 12.8MB (L3-served).
// Fallback (small ws): round-4 CSR-pairs pipeline.
// ---------------------------------------------------------------------------

__device__ __forceinline__ unsigned short f2bf(float f) {   // RTNE f32->bf16
    unsigned u = __float_as_uint(f);
    u = u + 0x7FFFu + ((u >> 16) & 1u);
    return (unsigned short)(u >> 16);
}
__device__ __forceinline__ float bflo(unsigned u) { return __uint_as_float(u << 16); }
__device__ __forceinline__ float bfhi(unsigned u) { return __uint_as_float(u & 0xffff0000u); }

__global__ void k_prep(const float* __restrict__ x, float* __restrict__ out2,
                       uint2* __restrict__ xb, int* __restrict__ cursor,
                       int* __restrict__ spillCnt, int n) {
    int gid = blockIdx.x * blockDim.x + threadIdx.x;
    if (gid == 0) *spillCnt = 0;
    if (gid < n) cursor[gid] = 0;
    if (gid >= n * 32) return;
    vfloat4 xv = reinterpret_cast<const vfloat4*>(x)[gid];
    __builtin_nontemporal_store(xv, reinterpret_cast<vfloat4*>(out2) + gid);
    uint2 b;
    b.x = (unsigned)f2bf(xv.x) | ((unsigned)f2bf(xv.y) << 16);
    b.y = (unsigned)f2bf(xv.z) | ((unsigned)f2bf(xv.w) << 16);
    xb[gid] = b;
}

// Group p (= blockIdx%8, tracking XCD round-robin) scans the whole edge list
// and places only destinations in its node range.
__global__ void k_place_ell(const int* __restrict__ row, const int* __restrict__ col,
                            int* __restrict__ cursor, int* __restrict__ ssrc,
                            int2* __restrict__ spill, int* __restrict__ spillCnt,
                            int e, int n) {
    int p  = blockIdx.x & (NPART - 1);
    int bg = blockIdx.x >> 3;
    int tg = bg * blockDim.x + threadIdx.x;
    int T  = (gridDim.x >> 3) * blockDim.x;
    int lo = (int)((long long)n * p / NPART);
    int hi = (int)((long long)n * (p + 1) / NPART);

    for (int i = tg; i < e; i += T) {
        int c = col[i];
        if (c < lo || c >= hi) continue;
        int r = row[i];
        int pos = atomicAdd(&cursor[c], 1);
        if (pos < WMAX) {
            ssrc[c * WMAX + pos] = r;
        } else {
            int s = atomicAdd(spillCnt, 1);
            if (s < SPILL_MAX) spill[s] = make_int2(r, c);
        }
    }
}

// One node per 64-lane wave; 4 nodes per 256-thread block.
// LDS-staged source list, counting-sorted by source slice; slice-major gathers.
__global__ void k_agg_sl(const unsigned* __restrict__ xbu, const float* __restrict__ bias,
                         const int* __restrict__ cursor, const int* __restrict__ ssrc,
                         const int2* __restrict__ spill, const int* __restrict__ spillCnt,
                         float* __restrict__ out, int n) {
    __shared__ int   s_srt[4][WMAX];
    __shared__ float s_wsrt[4][WMAX];
    __shared__ int   s_off[4][NSLICE + 1];

    int p  = blockIdx.x & (NPART - 1);
    int bg = blockIdx.x >> 3;
    int lo = (int)((long long)n * p / NPART);
    int hi = (int)((long long)n * (p + 1) / NPART);
    int t = threadIdx.x, wid = t >> 6, lane = t & 63;
    int node = lo + bg * 4 + wid;
    bool active = (node < hi);

    int cnt = active ? cursor[node] : 0;
    int m   = min(cnt, WMAX);

    if (lane <= NSLICE) s_off[wid][lane] = 0;
    __syncthreads();

    // load entry + weight, classify into slice, reserve sorted position
    int myslice = 0, mypos = 0, myr = 0;
    float myw = 0.f;
    bool have = active && (lane < m);
    if (have) {
        myr = ssrc[node * WMAX + lane];
        myw = rsqrtf((float)cursor[myr] + 1.0f);
        myslice = (int)(((long long)myr * NSLICE) / n);
        if (myslice > NSLICE - 1) myslice = NSLICE - 1;
        mypos = atomicAdd(&s_off[wid][myslice + 1], 1);
    }
    __syncthreads();
    if (lane == 0) {
        int acc = 0;
#pragma unroll
        for (int s2 = 1; s2 <= NSLICE; ++s2) { acc += s_off[wid][s2]; s_off[wid][s2] = acc; }
    }
    __syncthreads();
    if (have) {
        int wp = s_off[wid][myslice] + mypos;
        s_srt[wid][wp]  = myr;
        s_wsrt[wid][wp] = myw;
    }
    __syncthreads();

    if (!active) return;   // no barriers below

    float aLo = 0.f, aHi = 0.f, bLo = 0.f, bHi = 0.f;
#pragma unroll
    for (int s2 = 0; s2 < NSLICE; ++s2) {
        int j  = s_off[wid][s2];
        int je = s_off[wid][s2 + 1];
        for (; j + 2 <= je; j += 2) {
            int   r0 = s_srt[wid][j],     r1 = s_srt[wid][j + 1];
            float w0 = s_wsrt[wid][j],    w1 = s_wsrt[wid][j + 1];
            unsigned u0 = xbu[(size_t)r0 * 64 + lane];
            unsigned u1 = xbu[(size_t)r1 * 64 + lane];
            aLo += w0 * bflo(u0);  aHi += w0 * bfhi(u0);
            bLo += w1 * bflo(u1);  bHi += w1 * bfhi(u1);
        }
        if (j < je) {
            int   r0 = s_srt[wid][j];
            float w0 = s_wsrt[wid][j];
            unsigned u0 = xbu[(size_t)r0 * 64 + lane];
            aLo += w0 * bflo(u0);  aHi += w0 * bfhi(u0);
        }
    }

    // Overflow edges (normally zero): scan the tiny spill list.
    if (cnt > WMAX) {
        int sc = min(*spillCnt, SPILL_MAX);
        for (int s2 = 0; s2 < sc; ++s2) {
            int2 pr = spill[s2];
            if (pr.y == node) {
                float w = rsqrtf((float)cursor[pr.x] + 1.0f);
                unsigned u = xbu[(size_t)pr.x * 64 + lane];
                aLo += w * bflo(u);  aHi += w * bfhi(u);
            }
        }
    }

    float dc = rsqrtf((float)cnt + 1.0f);
    unsigned xc = xbu[(size_t)node * 64 + lane];
    float2 bv = reinterpret_cast<const float2*>(bias)[lane];
    vfloat2 ov;
    ov.x = bv.x + dc * (aLo + bLo + dc * bflo(xc));
    ov.y = bv.y + dc * (aHi + bHi + dc * bfhi(xc));
    __builtin_nontemporal_store(ov, reinterpret_cast<vfloat2*>(out) + (size_t)node * 64 + lane);
}

// ======================= fallback: round-4 CSR pipeline =======================

__global__ void k_zero(int* __restrict__ degInt, int n) {
    int i = blockIdx.x * blockDim.x + threadIdx.x;
    if (i < n) degInt[i] = 0;
}

__global__ void k_count(const int* __restrict__ col, int* __restrict__ degInt, int e) {
    int i = blockIdx.x * blockDim.x + threadIdx.x;
    if (i < e) atomicAdd(&degInt[col[i]], 1);
}

__global__ void k_scan1(const int* __restrict__ degInt, int* __restrict__ off,
                        int* __restrict__ bsum, int n) {
    __shared__ int sm[B];
    int i = blockIdx.x * B + threadIdx.x;
    int v = (i < n) ? degInt[i] : 0;
    sm[threadIdx.x] = v;
    __syncthreads();
    for (int s = 1; s < B; s <<= 1) {
        int t = (threadIdx.x >= (unsigned)s) ? sm[threadIdx.x - s] : 0;
        __syncthreads();
        sm[threadIdx.x] += t;
        __syncthreads();
    }
    if (i < n) off[i] = sm[threadIdx.x] - v;
    if (threadIdx.x == B - 1) bsum[blockIdx.x] = sm[B - 1];
}

__global__ void k_scan2(int* __restrict__ bsum, int nb) {
    __shared__ int sm[B];
    int v = (threadIdx.x < (unsigned)nb) ? bsum[threadIdx.x] : 0;
    sm[threadIdx.x] = v;
    __syncthreads();
    for (int s = 1; s < B; s <<= 1) {
        int t = (threadIdx.x >= (unsigned)s) ? sm[threadIdx.x - s] : 0;
        __syncthreads();
        sm[threadIdx.x] += t;
        __syncthreads();
    }
    if (threadIdx.x < (unsigned)nb) bsum[threadIdx.x] = sm[threadIdx.x] - v;
}

__global__ void k_scan3(int* __restrict__ off, const int* __restrict__ bsum,
                        const int* __restrict__ degInt, float* __restrict__ dis,
                        int* __restrict__ cursor, int n, int e) {
    int i = blockIdx.x * B + threadIdx.x;
    if (i < n) {
        int o = off[i] + bsum[blockIdx.x];
        off[i] = o;
        cursor[i] = o;
        dis[i] = rsqrtf((float)degInt[i] + 1.0f);
    }
    if (i == 0) off[n] = e;
}

__global__ void k_place_pairs(const int* __restrict__ row, const int* __restrict__ col,
                              const float* __restrict__ dis, int* __restrict__ cursor,
                              int2* __restrict__ pairs, int e) {
    int i = blockIdx.x * blockDim.x + threadIdx.x;
    if (i >= e) return;
    int r = row[i];
    int c = col[i];
    float w = dis[r];
    int pos = atomicAdd(&cursor[c], 1);
    pairs[pos] = make_int2(r, __float_as_int(w));
}

__global__ void k_aggregate_pairs(const float* __restrict__ x, const float* __restrict__ bias,
                                  const float* __restrict__ dis, const int* __restrict__ off,
                                  const int2* __restrict__ pairs, float* __restrict__ out,
                                  float* __restrict__ out2, int n) {
    int gid = blockIdx.x * blockDim.x + threadIdx.x;
    if (gid >= n * 32) return;
    int node = gid >> 5;
    int q    = gid & 31;
    const vfloat4* x4 = reinterpret_cast<const vfloat4*>(x);
    int j   = off[node];
    int end = off[node + 1];
    vfloat4 a0 = {0.f, 0.f, 0.f, 0.f};
    vfloat4 a1 = a0, a2 = a0, a3 = a0;
    for (; j + 4 <= end; j += 4) {
        int2 p0 = pairs[j + 0];
        int2 p1 = pairs[j + 1];
        int2 p2 = pairs[j + 2];
        int2 p3 = pairs[j + 3];
        vfloat4 v0 = x4[(size_t)p0.x * 32 + q];
        vfloat4 v1 = x4[(size_t)p1.x * 32 + q];
        vfloat4 v2 = x4[(size_t)p2.x * 32 + q];
        vfloat4 v3 = x4[(size_t)p3.x * 32 + q];
        a0 += __int_as_float(p0.y) * v0;
        a1 += __int_as_float(p1.y) * v1;
        a2 += __int_as_float(p2.y) * v2;
        a3 += __int_as_float(p3.y) * v3;
    }
    for (; j < end; ++j) {
        int2 p = pairs[j];
        a0 += __int_as_float(p.y) * x4[(size_t)p.x * 32 + q];
    }
    float dc = dis[node];
    vfloat4 xc = x4[(size_t)node * 32 + q];
    vfloat4 bv = reinterpret_cast<const vfloat4*>(bias)[q];
    vfloat4 ov = bv + dc * (a0 + a1 + a2 + a3 + dc * xc);
    __builtin_nontemporal_store(ov, reinterpret_cast<vfloat4*>(out)  + (size_t)node * 32 + q);
    __builtin_nontemporal_store(xc, reinterpret_cast<vfloat4*>(out2) + (size_t)node * 32 + q);
}

// =============================================================================

extern "C" void kernel_launch(void* const* d_in, const int* in_sizes, int n_in,
                              void* d_out, int out_size, void* d_ws, size_t ws_size,
                              hipStream_t stream) {
    const float* x    = (const float*)d_in[0];
    const int*   idx  = (const int*)d_in[1];   // [2, E]
    const float* bias = (const float*)d_in[2];

    const int n = in_sizes[0] / D;             // 50000
    const int e = in_sizes[1] / 2;             // 600000

    const int* row = idx;                      // sources
    const int* col = idx + e;                  // destinations

    float* out  = (float*)d_out;                     // [n, 128]
    float* out2 = (float*)d_out + (size_t)n * D;     // init_embeds

    const int nbN = (n + B - 1) / B;
    const int nbE = (e + B - 1) / B;
    const int prepB = (n * 32 + B - 1) / B;

    // ---- ELL + bf16 layout ----
    char* p0 = (char*)d_ws;
    int*  cursor  = (int*)p0;                        p0 += (size_t)n * 4;
    int*  spillCnt= (int*)p0;                        p0 += 16;
    int2* spill   = (int2*)p0;                       p0 += (size_t)SPILL_MAX * 8;
    p0 = (char*)(((uintptr_t)p0 + 15) & ~(uintptr_t)15);
    uint2* xb     = (uint2*)p0;                      p0 += (size_t)n * 32 * 8;   // bf16 x
    int*  ssrc    = (int*)p0;                        p0 += (size_t)n * WMAX * 4;
    size_t need_ell = (size_t)(p0 - (char*)d_ws);

    if (ws_size >= need_ell) {
        const int plB = 2048;   // 8 XCD groups x 256 blocks, all co-resident
        int maxPart = 0;
        for (int p = 0; p < NPART; ++p) {
            int lo = (int)((long long)n * p / NPART);
            int hi = (int)((long long)n * (p + 1) / NPART);
            if (hi - lo > maxPart) maxPart = hi - lo;
        }
        const int bpg = (maxPart + 3) / 4;             // 4 nodes per block
        const int agB = bpg * NPART;
        k_prep     <<<prepB, B, 0, stream>>>(x, out2, xb, cursor, spillCnt, n);
        k_place_ell<<<plB,   B, 0, stream>>>(row, col, cursor, ssrc, spill, spillCnt, e, n);
        k_agg_sl   <<<agB,   B, 0, stream>>>(reinterpret_cast<const unsigned*>(xb), bias,
                                             cursor, ssrc, spill, spillCnt, out, n);
        return;
    }

    // ---- fallback: round-4 CSR pipeline ----
    char* p = (char*)d_ws;
    int*   degInt = (int*)p;            p += (size_t)n * 4;
    int*   cur2   = (int*)p;            p += (size_t)n * 4;
    int*   off    = (int*)p;            p += (size_t)(n + 1) * 4;
    int*   bsum   = (int*)p;            p += 256 * 4;
    float* dis    = (float*)p;          p += (size_t)n * 4;
    p = (char*)(((uintptr_t)p + 15) & ~(uintptr_t)15);
    int2*  pairs  = (int2*)p;

    const int aggB = (n * 32 + B - 1) / B;
    k_zero <<<nbN, B, 0, stream>>>(degInt, n);
    k_count<<<nbE, B, 0, stream>>>(col, degInt, e);
    k_scan1<<<nbN, B, 0, stream>>>(degInt, off, bsum, n);
    k_scan2<<<1,   B, 0, stream>>>(bsum, nbN);
    k_scan3<<<nbN, B, 0, stream>>>(off, bsum, degInt, dis, cur2, n, e);
    k_place_pairs<<<nbE, B, 0, stream>>>(row, col, dis, cur2, pairs, e);
    k_aggregate_pairs<<<aggB, B, 0, stream>>>(x, bias, dis, off, pairs, out, out2, n);
}